// Round 1
// baseline (5843.539 us; speedup 1.0000x reference)
//
#include <hip/hip_runtime.h>
#include <math.h>

// Problem constants
#define BATCH  16384
#define HID    4096
#define NCOLS  1536     // NUM_SUB * H * 2
#define NGRP   384      // NUM_SUB * H / RANK

// GEMM tiling
#define BM 64
#define BN 64
#define BK 16

__device__ __forceinline__ double gumbel_d(float uu) {
    // g = -log(-log(u*(1-2*eps)+eps)), eps = 1e-6, in fp64
    double v = (double)uu * (1.0 - 2.0e-6) + 1.0e-6;
    return -log(-log(v));
}

// Fused GEMM (fp64 accumulation) + gumbel-softmax + group-score epilogue.
// x: (BATCH, HID) fp32 row-major; W: (HID, NCOLS) fp32 row-major; bias: (NCOLS,)
// u: (BATCH, NCOLS) fp32 (flattened (B, NUM_SUB, H, 2)); scores: (BATCH, NGRP) fp64
__global__ __launch_bounds__(256)
void gemm_score_kernel(const float* __restrict__ x, const float* __restrict__ W,
                       const float* __restrict__ bias, const float* __restrict__ u,
                       double* __restrict__ scores)
{
    __shared__ double As[BK][BM];   // 8 KB, k-major
    __shared__ double Bs[BK][BN];   // 8 KB, k-major

    const int t  = threadIdx.x;
    const int tx = t & 15;          // 16 column-groups (4 cols each = 1 score group)
    const int ty = t >> 4;          // 16 row-groups (4 rows each)
    const int row0 = blockIdx.y * BM;
    const int col0 = blockIdx.x * BN;

    // staging assignments
    const int ar = t >> 2;              // A row within tile (0..63)
    const int ak = (t & 3) << 2;        // A k-offset {0,4,8,12}
    const int bk = t >> 4;              // B k-row (0..15)
    const int bn = (t & 15) << 2;       // B col offset {0,4,...,60}

    const float* xp = x + (size_t)(row0 + ar) * HID + ak;
    const float* wp = W + (size_t)bk * NCOLS + col0 + bn;

    double acc[4][4] = {};

    for (int k0 = 0; k0 < HID; k0 += BK) {
        const float4 av = *(const float4*)(xp + k0);
        const float4 bv = *(const float4*)(wp + (size_t)k0 * NCOLS);
        __syncthreads();
        As[ak + 0][ar] = (double)av.x;
        As[ak + 1][ar] = (double)av.y;
        As[ak + 2][ar] = (double)av.z;
        As[ak + 3][ar] = (double)av.w;
        Bs[bk][bn + 0] = (double)bv.x;
        Bs[bk][bn + 1] = (double)bv.y;
        Bs[bk][bn + 2] = (double)bv.z;
        Bs[bk][bn + 3] = (double)bv.w;
        __syncthreads();
#pragma unroll
        for (int k = 0; k < BK; ++k) {
            const double a0 = As[k][ty * 4 + 0];
            const double a1 = As[k][ty * 4 + 1];
            const double a2 = As[k][ty * 4 + 2];
            const double a3 = As[k][ty * 4 + 3];
            const double b0 = Bs[k][tx * 4 + 0];
            const double b1 = Bs[k][tx * 4 + 1];
            const double b2 = Bs[k][tx * 4 + 2];
            const double b3 = Bs[k][tx * 4 + 3];
            acc[0][0] = fma(a0, b0, acc[0][0]);
            acc[0][1] = fma(a0, b1, acc[0][1]);
            acc[0][2] = fma(a0, b2, acc[0][2]);
            acc[0][3] = fma(a0, b3, acc[0][3]);
            acc[1][0] = fma(a1, b0, acc[1][0]);
            acc[1][1] = fma(a1, b1, acc[1][1]);
            acc[1][2] = fma(a1, b2, acc[1][2]);
            acc[1][3] = fma(a1, b3, acc[1][3]);
            acc[2][0] = fma(a2, b0, acc[2][0]);
            acc[2][1] = fma(a2, b1, acc[2][1]);
            acc[2][2] = fma(a2, b2, acc[2][2]);
            acc[2][3] = fma(a2, b3, acc[2][3]);
            acc[3][0] = fma(a3, b0, acc[3][0]);
            acc[3][1] = fma(a3, b1, acc[3][1]);
            acc[3][2] = fma(a3, b2, acc[3][2]);
            acc[3][3] = fma(a3, b3, acc[3][3]);
        }
    }

    // Epilogue: thread's 4 columns are exactly group g's [keep,drop] x 2 heads.
    const int g = (col0 >> 2) + tx;               // global group index 0..383
    const double bs0 = (double)bias[4 * g + 0];
    const double bs1 = (double)bias[4 * g + 1];
    const double bs2 = (double)bias[4 * g + 2];
    const double bs3 = (double)bias[4 * g + 3];
#pragma unroll
    for (int i = 0; i < 4; ++i) {
        const int row = row0 + ty * 4 + i;
        const float4 uv = *(const float4*)(u + (size_t)row * NCOLS + 4 * g);
        const double l0 = acc[i][0] + bs0;
        const double l1 = acc[i][1] + bs1;
        const double l2 = acc[i][2] + bs2;
        const double l3 = acc[i][3] + bs3;
        const double d0 = ((l0 + gumbel_d(uv.x)) - (l1 + gumbel_d(uv.y))) / 5.0;
        const double d1 = ((l2 + gumbel_d(uv.z)) - (l3 + gumbel_d(uv.w))) / 5.0;
        const double p0 = 1.0 / (1.0 + exp(-d0));   // softmax keep-prob, head 2j
        const double p1 = 1.0 / (1.0 + exp(-d1));   // head 2j+1
        scores[(size_t)row * NGRP + g] = 0.5 * (p0 + p1);
    }
}

// Per-sample top-budget selection + binary output write.
// Stable descending rank: rank[g] = #{j: s_j > s_g} + #{j: s_j == s_g, j < g}
// — exactly argsort(argsort(-scores)) with jax's stable sort.
__global__ __launch_bounds__(384)
void select_kernel(const double* __restrict__ scores, const float* __restrict__ latency,
                   float* __restrict__ out)
{
    __shared__ double sm[NGRP];
    const int b = blockIdx.x;
    const int t = threadIdx.x;

    const double sg = scores[(size_t)b * NGRP + t];
    sm[t] = sg;

    // budget = clip(round(lat*512), 128, 512) - 128 ; round-half-even like jnp.round
    float un = rintf(latency[b] * 512.0f);
    un = fminf(fmaxf(un, 128.0f), 512.0f);
    const int budget = (int)un - 128;

    __syncthreads();

    int rank = 0;
#pragma unroll 8
    for (int j = 0; j < NGRP; ++j) {
        const double sj = sm[j];  // same address across lanes -> LDS broadcast
        rank += (sj > sg || (sj == sg && j < t)) ? 1 : 0;
    }
    const float keep = (rank < budget) ? 1.0f : 0.0f;

    float* obase = out + (size_t)b * 2048;

    // prefix: layers 0..7 all ones (512 floats)
    if (t < 256) {
        *(float2*)(obase + 2 * t) = make_float2(1.0f, 1.0f);
    }

    // sub layer l = t>>4, heads 2j, 2j+1 with j = t&15
    const int l  = t >> 4;
    const int h2 = (t & 15) << 1;
    float* p = obase + (size_t)(8 + l) * 64;
    *(float2*)(p + h2)      = make_float2(keep, keep);               // s=0 (keep)
    *(float2*)(p + 32 + h2) = make_float2(1.0f - keep, 1.0f - keep); // s=1 (drop)
}

extern "C" void kernel_launch(void* const* d_in, const int* in_sizes, int n_in,
                              void* d_out, int out_size, void* d_ws, size_t ws_size,
                              hipStream_t stream) {
    const float* x       = (const float*)d_in[0];   // (16384, 4096)
    const float* latency = (const float*)d_in[1];   // (16384,)
    const float* W       = (const float*)d_in[2];   // (4096, 1536)
    const float* bias    = (const float*)d_in[3];   // (1536,)
    const float* u       = (const float*)d_in[4];   // (16384, 1536)
    float* out           = (float*)d_out;           // (16384, 32, 2, 32)

    double* scores = (double*)d_ws;                 // 16384*384*8 = 50.3 MB

    dim3 ggrid(NCOLS / BN, BATCH / BM);             // (24, 256)
    gemm_score_kernel<<<ggrid, 256, 0, stream>>>(x, W, bias, u, scores);
    select_kernel<<<BATCH, NGRP, 0, stream>>>(scores, latency, out);
}

// Round 2
// 4085.081 us; speedup vs baseline: 1.4305x; 1.4305x over previous
//
#include <hip/hip_runtime.h>
#include <math.h>

// Problem constants
#define BATCH  16384
#define HID    4096
#define NCOLS  1536     // NUM_SUB * H * 2
#define NGRP   384      // NUM_SUB * H / RANK

// GEMM tiling: 128x64 tile, 256 threads, 8x4 fp64 micro-tile
#define BM 128
#define BN 64
#define BK 16

__device__ __forceinline__ double gumbel_d(float uu) {
    // g = -log(-log(u*(1-2*eps)+eps)), eps = 1e-6, in fp64
    double v = (double)uu * (1.0 - 2.0e-6) + 1.0e-6;
    return -log(-log(v));
}

__device__ __forceinline__ int budget_of(float lat) {
    // round-half-even like jnp.round, clip to [128,512], shift by prefix units
    float un = rintf(lat * 512.0f);
    un = fminf(fmaxf(un, 128.0f), 512.0f);
    return (int)un - 128;   // 0..384
}

// Per-sample classification + trivial-output fill + compaction of interior rows.
// budget==0   -> all sub-layer heads dropped (keep=0): output fixed, skip GEMM
// budget==384 -> all kept: output fixed, skip GEMM
// Writes the prefix (layers 0..7 = ones) for ALL samples.
__global__ __launch_bounds__(64)
void prefilter_kernel(const float* __restrict__ latency, float* __restrict__ out,
                      int* __restrict__ count, int* __restrict__ idx)
{
    const int b = blockIdx.x;
    const int t = threadIdx.x;
    const int budget = budget_of(latency[b]);
    float* obase = out + (size_t)b * 2048;

    const float4 ones = make_float4(1.f, 1.f, 1.f, 1.f);
    ((float4*)obase)[t]      = ones;   // prefix: 512 floats = 128 float4
    ((float4*)obase)[t + 64] = ones;

    if (budget > 0 && budget < NGRP) {
        if (t == 0) { int s = atomicAdd(count, 1); idx[s] = b; }
    } else {
        const float K = (budget == 0) ? 0.0f : 1.0f;   // keep value for all heads
#pragma unroll
        for (int j = 0; j < 6; ++j) {
            const int i = j * 64 + t;        // float4 index within 1536-float region
            const int p = i * 4;             // float offset: p = l*64 + s*32 + h
            const int s = (p >> 5) & 1;
            const float v = s ? (1.0f - K) : K;
            ((float4*)(obase + 512))[i] = make_float4(v, v, v, v);
        }
    }
}

// Fused GEMM (fp64 FMA, fp32 LDS staging) + gumbel-softmax + group-score epilogue
// over compacted interior rows only.
__global__ __launch_bounds__(256)
void gemm_score_kernel(const float* __restrict__ x, const float* __restrict__ W,
                       const float* __restrict__ bias, const float* __restrict__ u,
                       const int* __restrict__ idx, const int* __restrict__ count,
                       double* __restrict__ scores)
{
    __shared__ float As[BK][BM + 4];   // [16][132] fp32, pad -> <=2-way (free)
    __shared__ float Bs[BK][BN + 4];   // [16][68]
    __shared__ int   rid[BM];

    const int cnt  = *count;
    const int row0 = blockIdx.y * BM;
    if (row0 >= cnt) return;
    const int col0 = blockIdx.x * BN;
    const int t    = threadIdx.x;

    if (t < BM) rid[t] = idx[min(row0 + t, cnt - 1)];
    __syncthreads();

    // staging assignments
    const int ar  = t >> 2;           // A row 0..63 (and ar+64)
    const int akc = (t & 3) << 2;     // A k-offset {0,4,8,12}
    const int bkr = t >> 4;           // B k-row 0..15
    const int bnc = (t & 15) << 2;    // B col offset {0,4,...,60}

    const size_t xoff0 = (size_t)rid[ar] * HID + akc;
    const size_t xoff1 = (size_t)rid[ar + 64] * HID + akc;
    const float* wp    = W + (size_t)bkr * NCOLS + col0 + bnc;

    const int ty = t >> 4;            // row-group 0..15 (8 rows)
    const int tx = t & 15;            // col-group 0..15 (4 cols = 1 score group)

    double acc[8][4] = {};

    // software pipeline: tile-0 loads in flight before loop
    float4 a0 = *(const float4*)(x + xoff0);
    float4 a1 = *(const float4*)(x + xoff1);
    float4 bv = *(const float4*)(wp);

    for (int k0 = 0; k0 < HID; k0 += BK) {
        __syncthreads();
        As[akc + 0][ar]      = a0.x;
        As[akc + 1][ar]      = a0.y;
        As[akc + 2][ar]      = a0.z;
        As[akc + 3][ar]      = a0.w;
        As[akc + 0][ar + 64] = a1.x;
        As[akc + 1][ar + 64] = a1.y;
        As[akc + 2][ar + 64] = a1.z;
        As[akc + 3][ar + 64] = a1.w;
        *(float4*)&Bs[bkr][bnc] = bv;
        __syncthreads();

        // prefetch next tile while computing this one
        if (k0 + BK < HID) {
            a0 = *(const float4*)(x + xoff0 + k0 + BK);
            a1 = *(const float4*)(x + xoff1 + k0 + BK);
            bv = *(const float4*)(wp + (size_t)(k0 + BK) * NCOLS);
        }

#pragma unroll
        for (int k = 0; k < BK; ++k) {
            const float4 af0 = *(const float4*)&As[k][ty * 8];
            const float4 af1 = *(const float4*)&As[k][ty * 8 + 4];
            const float4 bf  = *(const float4*)&Bs[k][tx * 4];
            double a[8], b[4];
            a[0] = (double)af0.x; a[1] = (double)af0.y; a[2] = (double)af0.z; a[3] = (double)af0.w;
            a[4] = (double)af1.x; a[5] = (double)af1.y; a[6] = (double)af1.z; a[7] = (double)af1.w;
            b[0] = (double)bf.x;  b[1] = (double)bf.y;  b[2] = (double)bf.z;  b[3] = (double)bf.w;
#pragma unroll
            for (int i = 0; i < 8; ++i)
#pragma unroll
                for (int j = 0; j < 4; ++j)
                    acc[i][j] = fma(a[i], b[j], acc[i][j]);
        }
    }

    // Epilogue: thread's 4 columns are exactly group g's [keep,drop] x 2 heads.
    const int g = (col0 >> 2) + tx;
    const double bs0 = (double)bias[4 * g + 0];
    const double bs1 = (double)bias[4 * g + 1];
    const double bs2 = (double)bias[4 * g + 2];
    const double bs3 = (double)bias[4 * g + 3];
#pragma unroll
    for (int i = 0; i < 8; ++i) {
        const int cr   = row0 + ty * 8 + i;          // compacted row
        const int orig = rid[ty * 8 + i];            // original sample
        const float4 uv = *(const float4*)(u + (size_t)orig * NCOLS + 4 * g);
        const double l0 = acc[i][0] + bs0;
        const double l1 = acc[i][1] + bs1;
        const double l2 = acc[i][2] + bs2;
        const double l3 = acc[i][3] + bs3;
        const double d0 = ((l0 + gumbel_d(uv.x)) - (l1 + gumbel_d(uv.y))) / 5.0;
        const double d1 = ((l2 + gumbel_d(uv.z)) - (l3 + gumbel_d(uv.w))) / 5.0;
        const double p0 = 1.0 / (1.0 + exp(-d0));
        const double p1 = 1.0 / (1.0 + exp(-d1));
        scores[(size_t)cr * NGRP + g] = 0.5 * (p0 + p1);
    }
}

// Per-interior-sample top-budget selection + binary sub-layer output write.
// Stable descending rank == argsort(argsort(-scores)) with jax's stable sort.
__global__ __launch_bounds__(384)
void select_kernel(const double* __restrict__ scores, const float* __restrict__ latency,
                   const int* __restrict__ idx, const int* __restrict__ count,
                   float* __restrict__ out)
{
    const int b = blockIdx.x;
    if (b >= *count) return;
    const int t = threadIdx.x;
    const int orig = idx[b];

    __shared__ double sm[NGRP];
    const double sg = scores[(size_t)b * NGRP + t];
    sm[t] = sg;
    const int budget = budget_of(latency[orig]);
    __syncthreads();

    int rank = 0;
#pragma unroll 8
    for (int j = 0; j < NGRP; ++j) {
        const double sj = sm[j];   // same address across lanes -> LDS broadcast
        rank += (sj > sg || (sj == sg && j < t)) ? 1 : 0;
    }
    const float keep = (rank < budget) ? 1.0f : 0.0f;

    // sub layer l = t>>4, heads 2j,2j+1 with j = t&15 (prefix written by prefilter)
    float* p = out + (size_t)orig * 2048 + 512 + (size_t)(t >> 4) * 64;
    const int h2 = (t & 15) << 1;
    *(float2*)(p + h2)      = make_float2(keep, keep);
    *(float2*)(p + 32 + h2) = make_float2(1.0f - keep, 1.0f - keep);
}

extern "C" void kernel_launch(void* const* d_in, const int* in_sizes, int n_in,
                              void* d_out, int out_size, void* d_ws, size_t ws_size,
                              hipStream_t stream) {
    const float* x       = (const float*)d_in[0];   // (16384, 4096)
    const float* latency = (const float*)d_in[1];   // (16384,)
    const float* W       = (const float*)d_in[2];   // (4096, 1536)
    const float* bias    = (const float*)d_in[3];   // (1536,)
    const float* u       = (const float*)d_in[4];   // (16384, 1536)
    float* out           = (float*)d_out;           // (16384, 32, 2, 32)

    // workspace layout: [count:4B pad to 256] [idx: 16384*4B] [scores: 16384*384*8B]
    int*    count  = (int*)d_ws;
    int*    idx    = (int*)((char*)d_ws + 256);
    double* scores = (double*)((char*)d_ws + 256 + 65536);

    hipMemsetAsync(d_ws, 0, 256, stream);
    prefilter_kernel<<<BATCH, 64, 0, stream>>>(latency, out, count, idx);
    dim3 ggrid(NCOLS / BN, BATCH / BM);   // (24, 128); row-blocks past count exit early
    gemm_score_kernel<<<ggrid, 256, 0, stream>>>(x, W, bias, u, idx, count, scores);
    select_kernel<<<BATCH, NGRP, 0, stream>>>(scores, latency, idx, count, out);
}

// Round 3
// 3137.926 us; speedup vs baseline: 1.8622x; 1.3018x over previous
//
#include <hip/hip_runtime.h>
#include <math.h>

// Problem constants
#define BATCH  16384
#define HID    4096
#define NCOLS  1536     // NUM_SUB * H * 2
#define NGRP   384      // NUM_SUB * H / RANK

// Safety margin for fp32-vs-fp64 score agreement (|err| <= ~2e-6 worst case;
// 2e-5 is a ~60-sigma margin). Samples with boundary gap below this are
// recomputed in fp64.
#define GAP_MIN 2.0e-5f

__device__ __forceinline__ int budget_of(float lat) {
    float un = rintf(lat * 512.0f);           // round-half-even like jnp.round
    un = fminf(fmaxf(un, 128.0f), 512.0f);
    return (int)un - 128;                     // 0..384
}

__device__ __forceinline__ double gumbel_d(float uu) {
    double v = (double)uu * (1.0 - 2.0e-6) + 1.0e-6;
    return -log(-log(v));
}

// fp32 gumbel, accurate at BOTH tails. For u>0.5, -log(v)=-log(1-w) with
// w = (1-u) + 1e-6*(2u-1): (1-u) and (2u-1) are exact (Sterbenz), so w has
// ~1ulp relative error and log1pf keeps the tiny inner value accurate.
__device__ __forceinline__ float gumbel_f(float u) {
    float inner;
    if (u <= 0.5f) {
        float v = fmaf(u, 0.999998f, 1e-6f);          // u*(1-2e-6)+1e-6
        inner = -logf(v);
    } else {
        float t1 = 1.0f - u;                          // exact
        float w  = fmaf(1e-6f, fmaf(2.0f, u, -1.0f), t1);
        inner = -log1pf(-w);
    }
    return -logf(inner);
}

__device__ __forceinline__ float score_f(float l0, float l1, float l2, float l3,
                                         float4 uv) {
    const float d0 = ((l0 + gumbel_f(uv.x)) - (l1 + gumbel_f(uv.y))) * 0.2f;
    const float d1 = ((l2 + gumbel_f(uv.z)) - (l3 + gumbel_f(uv.w))) * 0.2f;
    const float p0 = 1.0f / (1.0f + expf(-d0));
    const float p1 = 1.0f / (1.0f + expf(-d1));
    return 0.5f * (p0 + p1);
}

// Per-sample classification + trivial-output fill + compaction of interior rows.
__global__ __launch_bounds__(64)
void prefilter_kernel(const float* __restrict__ latency, float* __restrict__ out,
                      int* __restrict__ count, int* __restrict__ idx)
{
    const int b = blockIdx.x;
    const int t = threadIdx.x;
    const int budget = budget_of(latency[b]);
    float* obase = out + (size_t)b * 2048;

    const float4 ones = make_float4(1.f, 1.f, 1.f, 1.f);
    ((float4*)obase)[t]      = ones;   // prefix: layers 0..7 all ones
    ((float4*)obase)[t + 64] = ones;

    if (budget > 0 && budget < NGRP) {
        if (t == 0) { int s = atomicAdd(count, 1); idx[s] = b; }
    } else {
        const float K = (budget == 0) ? 0.0f : 1.0f;
#pragma unroll
        for (int j = 0; j < 6; ++j) {
            const int i = j * 64 + t;
            const int p = i * 4;             // p = l*64 + s*32 + h
            const int s = (p >> 5) & 1;
            const float v = s ? (1.0f - K) : K;
            ((float4*)(obase + 512))[i] = make_float4(v, v, v, v);
        }
    }
}

// Fast fp32 GEMM (128x128 tile, 8x8 micro) + fp32 gumbel-softmax scores.
__global__ __launch_bounds__(256)
void gemm32_kernel(const float* __restrict__ x, const float* __restrict__ W,
                   const float* __restrict__ bias, const float* __restrict__ u,
                   const int* __restrict__ idx, const int* __restrict__ count,
                   float* __restrict__ scoresf)
{
    __shared__ float As[16][132];
    __shared__ float Bs[16][132];
    __shared__ int   rid[128];

    const int cnt  = *count;
    const int row0 = blockIdx.y * 128;
    if (row0 >= cnt) return;
    const int col0 = blockIdx.x * 128;
    const int t    = threadIdx.x;

    if (t < 128) rid[t] = idx[min(row0 + t, cnt - 1)];
    __syncthreads();

    const int ar  = t >> 2;             // A row 0..63 (and +64)
    const int akc = (t & 3) << 2;       // A k-offset {0,4,8,12}
    const int bkr = t >> 4;             // B k-row 0..15
    const int bnc = (t & 15) << 2;      // B col offset {0..60} (and +64)

    const size_t xoff0 = (size_t)rid[ar] * HID + akc;
    const size_t xoff1 = (size_t)rid[ar + 64] * HID + akc;
    const float* wp    = W + (size_t)bkr * NCOLS + col0 + bnc;

    const int ty = t >> 4;              // row group: rows ty*8..+7
    const int tx = t & 15;              // col groups: tx*4..+3 and 64+tx*4..+3

    float acc[8][8] = {};

    float4 a0 = *(const float4*)(x + xoff0);
    float4 a1 = *(const float4*)(x + xoff1);
    float4 b0 = *(const float4*)(wp);
    float4 b1 = *(const float4*)(wp + 64);

    for (int k0 = 0; k0 < HID; k0 += 16) {
        __syncthreads();
        As[akc + 0][ar]      = a0.x; As[akc + 1][ar]      = a0.y;
        As[akc + 2][ar]      = a0.z; As[akc + 3][ar]      = a0.w;
        As[akc + 0][ar + 64] = a1.x; As[akc + 1][ar + 64] = a1.y;
        As[akc + 2][ar + 64] = a1.z; As[akc + 3][ar + 64] = a1.w;
        *(float4*)&Bs[bkr][bnc]      = b0;
        *(float4*)&Bs[bkr][bnc + 64] = b1;
        __syncthreads();

        if (k0 + 16 < HID) {
            a0 = *(const float4*)(x + xoff0 + k0 + 16);
            a1 = *(const float4*)(x + xoff1 + k0 + 16);
            b0 = *(const float4*)(wp + (size_t)(k0 + 16) * NCOLS);
            b1 = *(const float4*)(wp + (size_t)(k0 + 16) * NCOLS + 64);
        }

#pragma unroll
        for (int k = 0; k < 16; ++k) {
            const float4 af0 = *(const float4*)&As[k][ty * 8];
            const float4 af1 = *(const float4*)&As[k][ty * 8 + 4];
            const float4 bf0 = *(const float4*)&Bs[k][tx * 4];
            const float4 bf1 = *(const float4*)&Bs[k][tx * 4 + 64];
            const float a[8] = {af0.x, af0.y, af0.z, af0.w, af1.x, af1.y, af1.z, af1.w};
            const float b[8] = {bf0.x, bf0.y, bf0.z, bf0.w, bf1.x, bf1.y, bf1.z, bf1.w};
#pragma unroll
            for (int i = 0; i < 8; ++i)
#pragma unroll
                for (int j = 0; j < 8; ++j)
                    acc[i][j] = fmaf(a[i], b[j], acc[i][j]);
        }
    }

    const int g0 = (col0 >> 2) + tx;      // group of cols col0+4tx..+3
    const int g1 = g0 + 16;               // group of cols col0+64+4tx..+3
    const float4 bs0 = *(const float4*)(bias + 4 * g0);
    const float4 bs1 = *(const float4*)(bias + 4 * g1);
#pragma unroll
    for (int i = 0; i < 8; ++i) {
        const int rl   = ty * 8 + i;
        const int cr   = row0 + rl;
        const int orig = rid[rl];
        const float4 uv0 = *(const float4*)(u + (size_t)orig * NCOLS + 4 * g0);
        const float4 uv1 = *(const float4*)(u + (size_t)orig * NCOLS + 4 * g1);
        scoresf[(size_t)cr * NGRP + g0] =
            score_f(acc[i][0] + bs0.x, acc[i][1] + bs0.y,
                    acc[i][2] + bs0.z, acc[i][3] + bs0.w, uv0);
        scoresf[(size_t)cr * NGRP + g1] =
            score_f(acc[i][4] + bs1.x, acc[i][5] + bs1.y,
                    acc[i][6] + bs1.z, acc[i][7] + bs1.w, uv1);
    }
}

// fp32 selection with boundary-gap certification; flags close calls for fp64.
__global__ __launch_bounds__(384)
void select_fast(const float* __restrict__ scoresf, const float* __restrict__ latency,
                 const int* __restrict__ idx, const int* __restrict__ count,
                 float* __restrict__ out, int* __restrict__ ridx, int* __restrict__ rcount)
{
    const int b = blockIdx.x;
    if (b >= *count) return;
    const int t = threadIdx.x;
    const int orig = idx[b];

    __shared__ float sm[NGRP];
    __shared__ float bnd[2];
    __shared__ int   flag;
    const float sg = scoresf[(size_t)b * NGRP + t];
    sm[t] = sg;
    if (t == 0) flag = 0;
    const int budget = budget_of(latency[orig]);   // 1..383 here
    __syncthreads();

    int rank = 0;
#pragma unroll 8
    for (int j = 0; j < NGRP; ++j) {
        const float sj = sm[j];
        rank += (sj > sg || (sj == sg && j < t)) ? 1 : 0;
    }
    if (rank == budget - 1) bnd[0] = sg;   // min of kept set
    if (rank == budget)     bnd[1] = sg;   // max of dropped set
    __syncthreads();
    if (t == 0 && (bnd[0] - bnd[1] < GAP_MIN)) {
        flag = 1;
        ridx[atomicAdd(rcount, 1)] = orig;
    }
    __syncthreads();
    if (flag) return;

    const float keep = (rank < budget) ? 1.0f : 0.0f;
    float* p = out + (size_t)orig * 2048 + 512 + (size_t)(t >> 4) * 64;
    const int h2 = (t & 15) << 1;
    *(float2*)(p + h2)      = make_float2(keep, keep);
    *(float2*)(p + 32 + h2) = make_float2(1.0f - keep, 1.0f - keep);
}

// fp64 repair GEMM over flagged rows only. BM=32 for block-level parallelism.
__global__ __launch_bounds__(256)
void gemm64_repair(const float* __restrict__ x, const float* __restrict__ W,
                   const float* __restrict__ bias, const float* __restrict__ u,
                   const int* __restrict__ ridx, const int* __restrict__ rcount,
                   double* __restrict__ scores)
{
    __shared__ float As[16][36];
    __shared__ float Bs[16][68];
    __shared__ int   rid[32];

    const int cnt  = *rcount;
    const int row0 = blockIdx.y * 32;
    if (row0 >= cnt) return;
    const int col0 = blockIdx.x * 64;
    const int t    = threadIdx.x;

    if (t < 32) rid[t] = ridx[min(row0 + t, cnt - 1)];
    __syncthreads();

    const bool doA = (t < 128);
    const int ar  = t >> 2;            // 0..31 when doA
    const int akc = (t & 3) << 2;
    const int bkr = t >> 4;
    const int bnc = (t & 15) << 2;

    size_t xoff = 0;
    if (doA) xoff = (size_t)rid[ar] * HID + akc;
    const float* wp = W + (size_t)bkr * NCOLS + col0 + bnc;

    const int ty = t >> 4;             // rows 2ty, 2ty+1
    const int tx = t & 15;

    double acc[2][4] = {};

    float4 a0 = make_float4(0, 0, 0, 0);
    if (doA) a0 = *(const float4*)(x + xoff);
    float4 b0 = *(const float4*)(wp);

    for (int k0 = 0; k0 < HID; k0 += 16) {
        __syncthreads();
        if (doA) {
            As[akc + 0][ar] = a0.x; As[akc + 1][ar] = a0.y;
            As[akc + 2][ar] = a0.z; As[akc + 3][ar] = a0.w;
        }
        *(float4*)&Bs[bkr][bnc] = b0;
        __syncthreads();
        if (k0 + 16 < HID) {
            if (doA) a0 = *(const float4*)(x + xoff + k0 + 16);
            b0 = *(const float4*)(wp + (size_t)(k0 + 16) * NCOLS);
        }
#pragma unroll
        for (int k = 0; k < 16; ++k) {
            const double a0d = (double)As[k][ty * 2];
            const double a1d = (double)As[k][ty * 2 + 1];
            const float4 bf  = *(const float4*)&Bs[k][tx * 4];
            const double bd[4] = {(double)bf.x, (double)bf.y, (double)bf.z, (double)bf.w};
#pragma unroll
            for (int j = 0; j < 4; ++j) {
                acc[0][j] = fma(a0d, bd[j], acc[0][j]);
                acc[1][j] = fma(a1d, bd[j], acc[1][j]);
            }
        }
    }

    const int g = (col0 >> 2) + tx;
    const double bs0 = (double)bias[4 * g + 0];
    const double bs1 = (double)bias[4 * g + 1];
    const double bs2 = (double)bias[4 * g + 2];
    const double bs3 = (double)bias[4 * g + 3];
#pragma unroll
    for (int i = 0; i < 2; ++i) {
        const int rl   = ty * 2 + i;
        const int cr   = row0 + rl;
        const int orig = rid[rl];
        const float4 uv = *(const float4*)(u + (size_t)orig * NCOLS + 4 * g);
        const double l0 = acc[i][0] + bs0;
        const double l1 = acc[i][1] + bs1;
        const double l2 = acc[i][2] + bs2;
        const double l3 = acc[i][3] + bs3;
        const double d0 = ((l0 + gumbel_d(uv.x)) - (l1 + gumbel_d(uv.y))) / 5.0;
        const double d1 = ((l2 + gumbel_d(uv.z)) - (l3 + gumbel_d(uv.w))) / 5.0;
        const double p0 = 1.0 / (1.0 + exp(-d0));
        const double p1 = 1.0 / (1.0 + exp(-d1));
        scores[(size_t)cr * NGRP + g] = 0.5 * (p0 + p1);
    }
}

// fp64 selection for flagged rows (no gap test).
__global__ __launch_bounds__(384)
void select_repair(const double* __restrict__ scores, const float* __restrict__ latency,
                   const int* __restrict__ ridx, const int* __restrict__ rcount,
                   float* __restrict__ out)
{
    const int b = blockIdx.x;
    if (b >= *rcount) return;
    const int t = threadIdx.x;
    const int orig = ridx[b];

    __shared__ double sm[NGRP];
    const double sg = scores[(size_t)b * NGRP + t];
    sm[t] = sg;
    const int budget = budget_of(latency[orig]);
    __syncthreads();

    int rank = 0;
#pragma unroll 8
    for (int j = 0; j < NGRP; ++j) {
        const double sj = sm[j];
        rank += (sj > sg || (sj == sg && j < t)) ? 1 : 0;
    }
    const float keep = (rank < budget) ? 1.0f : 0.0f;

    float* p = out + (size_t)orig * 2048 + 512 + (size_t)(t >> 4) * 64;
    const int h2 = (t & 15) << 1;
    *(float2*)(p + h2)      = make_float2(keep, keep);
    *(float2*)(p + 32 + h2) = make_float2(1.0f - keep, 1.0f - keep);
}

extern "C" void kernel_launch(void* const* d_in, const int* in_sizes, int n_in,
                              void* d_out, int out_size, void* d_ws, size_t ws_size,
                              hipStream_t stream) {
    const float* x       = (const float*)d_in[0];
    const float* latency = (const float*)d_in[1];
    const float* W       = (const float*)d_in[2];
    const float* bias    = (const float*)d_in[3];
    const float* u       = (const float*)d_in[4];
    float* out           = (float*)d_out;

    // ws layout: [count,rcount.. 256B] [idx 64KB] [ridx 64KB] [big region]
    // big region: scoresf (fp32, 25.2MB) and scores64 (fp64, 50.3MB) ALIASED —
    // lifetimes are disjoint (select_fast finishes before gemm64_repair writes).
    int*    count   = (int*)d_ws;
    int*    rcount  = (int*)((char*)d_ws + 4);
    int*    idx     = (int*)((char*)d_ws + 256);
    int*    ridx    = (int*)((char*)d_ws + 256 + 65536);
    float*  scoresf = (float*)((char*)d_ws + 256 + 131072);
    double* scores64= (double*)((char*)d_ws + 256 + 131072);

    hipMemsetAsync(d_ws, 0, 256, stream);
    prefilter_kernel<<<BATCH, 64, 0, stream>>>(latency, out, count, idx);
    gemm32_kernel<<<dim3(NCOLS / 128, BATCH / 128), 256, 0, stream>>>(
        x, W, bias, u, idx, count, scoresf);
    select_fast<<<BATCH, NGRP, 0, stream>>>(scoresf, latency, idx, count, out, ridx, rcount);
    gemm64_repair<<<dim3(NCOLS / 64, BATCH / 32), 256, 0, stream>>>(
        x, W, bias, u, ridx, rcount, scores64);
    select_repair<<<BATCH, NGRP, 0, stream>>>(scores64, latency, ridx, rcount, out);
}